// Round 6
// baseline (506.906 us; speedup 1.0000x reference)
//
#include <hip/hip_runtime.h>

typedef unsigned short u16;
typedef unsigned int u32;
typedef __attribute__((ext_vector_type(8))) short short8;
typedef __attribute__((ext_vector_type(4))) float floatx4;

// ---------- bf16 helpers ----------
__device__ __forceinline__ float b2f(u32 bits) { union { u32 u; float f; } c; c.u = bits << 16; return c.f; }
__device__ __forceinline__ float b2f_lo(u32 w) { union { u32 u; float f; } c; c.u = w << 16; return c.f; }
__device__ __forceinline__ float b2f_hi(u32 w) { union { u32 u; float f; } c; c.u = w & 0xFFFF0000u; return c.f; }
__device__ __forceinline__ u16 f2b(float f) {
    union { float f; u32 u; } c; c.f = f;
    u32 u = c.u;
    return (u16)((u + 0x7FFFu + ((u >> 16) & 1u)) >> 16);   // RNE
}
// packed bf16 mul, round-half-up (bias ~2^-16 rel)
__device__ __forceinline__ u32 pkmul(u32 a, u32 b) {
    union { u32 u; float f; } alo, ahi, blo, bhi, rlo, rhi;
    alo.u = a << 16; ahi.u = a & 0xFFFF0000u;
    blo.u = b << 16; bhi.u = b & 0xFFFF0000u;
    rlo.f = alo.f * blo.f; rhi.f = ahi.f * bhi.f;
    u32 lo = rlo.u + 0x8000u, hi = rhi.u + 0x8000u;
    return __builtin_amdgcn_perm(hi, lo, 0x07060302u);
}
// async global->LDS, 16B per lane; lds base must be wave-uniform
__device__ __forceinline__ void gld_lds16(const u16* g, u16* l) {
    __builtin_amdgcn_global_load_lds((const __attribute__((address_space(1))) u32*)g,
                                     (__attribute__((address_space(3))) u32*)l, 16, 0, 0);
}

// ---------- graph prep ----------
__global__ __launch_bounds__(256) void count_deg(const int* __restrict__ row, int* __restrict__ cnt, int E) {
    int e = blockIdx.x * 256 + threadIdx.x;
    if (e < E) atomicAdd(&cnt[row[e]], 1);
}

__global__ __launch_bounds__(256) void deg_psum(const int* __restrict__ cnt, int* __restrict__ bsum, int N) {
    __shared__ int sc[256];
    int t = threadIdx.x, i = blockIdx.x * 256 + t;
    sc[t] = (i < N) ? cnt[i] : 0;
    __syncthreads();
    for (int o = 128; o > 0; o >>= 1) {
        if (t < o) sc[t] += sc[t + o];
        __syncthreads();
    }
    if (t == 0) bsum[blockIdx.x] = sc[0];
}

__global__ __launch_bounds__(256) void scan_bsum(const int* __restrict__ bsum, int* __restrict__ ebsum,
                                                 int NB, int* __restrict__ offs, int N, int E) {
    __shared__ int sc[256];
    int t = threadIdx.x;
    int v = (t < NB) ? bsum[t] : 0;
    sc[t] = v;
    __syncthreads();
    for (int o = 1; o < 256; o <<= 1) {
        int u = (t >= o) ? sc[t - o] : 0;
        __syncthreads();
        sc[t] += u;
        __syncthreads();
    }
    if (t < NB) ebsum[t] = sc[t] - v;
    if (t == 0) offs[N] = E;
}

__global__ __launch_bounds__(256) void write_offs(const int* __restrict__ cnt, const int* __restrict__ ebsum,
                                                  int* __restrict__ offs, float* __restrict__ dinv, int N) {
    __shared__ int sc[256];
    int t = threadIdx.x, i = blockIdx.x * 256 + t;
    int v = (i < N) ? cnt[i] : 0;
    sc[t] = v;
    __syncthreads();
    for (int o = 1; o < 256; o <<= 1) {
        int u = (t >= o) ? sc[t - o] : 0;
        __syncthreads();
        sc[t] += u;
        __syncthreads();
    }
    if (i < N) {
        offs[i] = ebsum[blockIdx.x] + sc[t] - v;
        dinv[i] = rsqrtf((float)v + 1.0f);
    }
}

__global__ __launch_bounds__(256) void sort_edges(const int* __restrict__ row, const int* __restrict__ col,
                                                  const int* __restrict__ offs, int* __restrict__ cursor,
                                                  int* __restrict__ scol, int E) {
    int e = blockIdx.x * 256 + threadIdx.x;
    if (e < E) {
        int r = row[e];
        int p = offs[r] + atomicAdd(&cursor[r], 1);
        scol[p] = col[e];
    }
}

// ---------- weight prep: WT[which][n][k] = bf16(W[k][n]) ----------
__global__ __launch_bounds__(256) void prep_w(const float* __restrict__ W1, const float* __restrict__ W2,
                                              const float* __restrict__ pW1, u16* __restrict__ WT) {
    int tid = blockIdx.x * 256 + threadIdx.x;
    int which = tid >> 16, id = tid & 65535;
    int n = id >> 8, k = id & 255;
    const float* W = (which == 0) ? W1 : ((which == 1) ? W2 : pW1);
    WT[tid] = f2b(W[k * 256 + n]);
}

// ---------- h0 = bf16(concat(emb, x)) ----------
__global__ __launch_bounds__(256) void concat_h0(const float* __restrict__ emb, const float* __restrict__ x,
                                                 u16* __restrict__ h0b, int N) {
    int t = blockIdx.x * 256 + threadIdx.x;
    long base = (long)t * 4;
    if (base >= (long)N * 256) return;
    int i = (int)(base >> 8), k = (int)(base & 255);
    const float* src = (k < 128) ? (emb + (long)i * 128 + k) : (x + (long)i * 128 + (k - 128));
    float4 v = *(const float4*)src;
    ushort4 o;
    o.x = f2b(v.x); o.y = f2b(v.y); o.z = f2b(v.z); o.w = f2b(v.w);
    *(ushort4*)(h0b + base) = o;
}

// ---------- aggregation: 1 node per half-wave (32 lanes x uint4 = full 512B row) ----------
// FUSED_BN: input transform x' = relu(x*scale + shift) applied to every gathered element
template <int FUSED_BN>
__global__ __launch_bounds__(256) void aggregate2(const u16* __restrict__ h, const int* __restrict__ offs,
                                                  const int* __restrict__ scol, const float* __restrict__ dinv,
                                                  const float* __restrict__ coef, u16* __restrict__ out, int N) {
    int hw = threadIdx.x >> 5, lane = threadIdx.x & 31;
    int node = blockIdx.x * 8 + hw;
    if (node >= N) return;
    float sc[8], sh[8];
    if (FUSED_BN) {
#pragma unroll
        for (int i = 0; i < 8; i++) { sc[i] = coef[lane * 8 + i]; sh[i] = coef[256 + lane * 8 + i]; }
    }
    float a[8];
#pragma unroll
    for (int i = 0; i < 8; i++) a[i] = 0.f;

    auto rowAcc = [&](uint4 u, float d) {
        float f[8];
        f[0] = b2f_lo(u.x); f[1] = b2f_hi(u.x);
        f[2] = b2f_lo(u.y); f[3] = b2f_hi(u.y);
        f[4] = b2f_lo(u.z); f[5] = b2f_hi(u.z);
        f[6] = b2f_lo(u.w); f[7] = b2f_hi(u.w);
#pragma unroll
        for (int i = 0; i < 8; i++) {
            float v = f[i];
            if (FUSED_BN) v = fmaxf(fmaf(v, sc[i], sh[i]), 0.f);
            a[i] = fmaf(v, d, a[i]);
        }
    };
    int beg = offs[node], end = offs[node + 1];
    int j = beg;
    for (; j + 3 < end; j += 4) {
        int c0 = scol[j], c1 = scol[j + 1], c2 = scol[j + 2], c3 = scol[j + 3];
        float d0 = dinv[c0], d1 = dinv[c1], d2 = dinv[c2], d3 = dinv[c3];
        uint4 v0 = *(const uint4*)(h + (long)c0 * 256 + lane * 8);
        uint4 v1 = *(const uint4*)(h + (long)c1 * 256 + lane * 8);
        uint4 v2 = *(const uint4*)(h + (long)c2 * 256 + lane * 8);
        uint4 v3 = *(const uint4*)(h + (long)c3 * 256 + lane * 8);
        rowAcc(v0, d0); rowAcc(v1, d1); rowAcc(v2, d2); rowAcc(v3, d3);
    }
    for (; j < end; j++) {
        int c0 = scol[j];
        float d0 = dinv[c0];
        uint4 v0 = *(const uint4*)(h + (long)c0 * 256 + lane * 8);
        rowAcc(v0, d0);
    }
    float di = dinv[node];
    {
        uint4 u = *(const uint4*)(h + (long)node * 256 + lane * 8);
        rowAcc(u, di);   // self term with weight di (total = sum + di*self)
    }
    u16 ob[8];
#pragma unroll
    for (int i = 0; i < 8; i++) ob[i] = f2b(di * a[i]);
    ushort4 o0, o1;
    o0.x = ob[0]; o0.y = ob[1]; o0.z = ob[2]; o0.w = ob[3];
    o1.x = ob[4]; o1.y = ob[5]; o1.z = ob[6]; o1.w = ob[7];
    *(ushort4*)(out + (long)node * 256 + lane * 8) = o0;
    *(ushort4*)(out + (long)node * 256 + lane * 8 + 4) = o1;
}

// ---------- GEMM: C_bf16[M][256] = A_bf16[M][256] @ B + bias; optional BN column stats ----------
// 16 rows/wave (acc=64 AGPR + za=32 VGPR): fits the 256-reg/wave cap of (512,2) with NO spill.
// (R5 lesson: 32 rows/wave needed ~290 regs -> allocator spilled acc to L2-backed scratch -> 40x stall)
template <int STATS>
__global__ __launch_bounds__(512, 2) void gemm_big(const u16* __restrict__ A, const u16* __restrict__ BT,
                                                   const float* __restrict__ bias, u16* __restrict__ C,
                                                   float* __restrict__ sums, int M) {
    __shared__ u16 Bs[128 * 256];   // 64 KB
    int tid = threadIdx.x;
    int wave = tid >> 6, lane = tid & 63, l15 = lane & 15, quad = lane >> 4;
    int row16 = blockIdx.x * 128 + wave * 16;
    long arow = min(row16 + l15, M - 1);
    short8 za[8];
#pragma unroll
    for (int ki = 0; ki < 8; ki++)
        za[ki] = *(const short8*)(A + arow * 256 + ki * 32 + quad * 8);

    floatx4 acc[16];
    floatx4 zero = {0.f, 0.f, 0.f, 0.f};
#pragma unroll
    for (int j = 0; j < 16; j++) acc[j] = zero;

#pragma unroll
    for (int p = 0; p < 2; p++) {
        {
            int nl = tid >> 2, cg = (tid & 3) * 8;
            const uint4* src = (const uint4*)(BT + (long)(p * 128 + nl) * 256);
#pragma unroll
            for (int c8 = 0; c8 < 8; c8++) {
                int c = cg + c8;
                int cs = c ^ (nl & 7);
                *(uint4*)(Bs + nl * 256 + cs * 8) = src[c];
            }
        }
        __syncthreads();
#pragma unroll
        for (int ki = 0; ki < 8; ki++) {
#pragma unroll
            for (int nt = 0; nt < 8; nt++) {
                int nl = nt * 16 + l15;
                int cs = (ki * 4 + quad) ^ (l15 & 7);
                short8 b = *(const short8*)(Bs + nl * 256 + cs * 8);
                acc[p * 8 + nt] = __builtin_amdgcn_mfma_f32_16x16x32_bf16(za[ki], b, acc[p * 8 + nt], 0, 0, 0);
            }
        }
        __syncthreads();
    }
#pragma unroll
    for (int j = 0; j < 16; j++) {
        int col = (j >> 3) * 128 + (j & 7) * 16 + l15;
        float bv = bias[col];
        float s = 0.f, s2 = 0.f;
#pragma unroll
        for (int r = 0; r < 4; r++) {
            int row = row16 + quad * 4 + r;
            float val = acc[j][r] + bv;
            if (row < M) {
                C[(long)row * 256 + col] = f2b(val);
                if (STATS) { s += val; s2 = fmaf(val, val, s2); }
            }
        }
        if (STATS) {
            s += __shfl_xor(s, 16, 64); s += __shfl_xor(s, 32, 64);
            s2 += __shfl_xor(s2, 16, 64); s2 += __shfl_xor(s2, 32, 64);
            if (quad == 0) {
                unsafeAtomicAdd(&sums[col], s);
                unsafeAtomicAdd(&sums[256 + col], s2);
            }
        }
    }
}

// ---------- BN coefficients: scale/shift per column ----------
__global__ __launch_bounds__(256) void bn_coef(const float* __restrict__ sums, const float* __restrict__ gamma,
                                               const float* __restrict__ beta, float* __restrict__ coef, int N) {
    int c = threadIdx.x;
    float invN = 1.0f / (float)N;
    float mean = sums[c] * invN;
    float var = sums[256 + c] * invN - mean * mean;
    float s = gamma[c] * rsqrtf(var + 1e-5f);
    coef[c] = s;
    coef[256 + c] = beta[c] - mean * s;
}

// ---------- predictor v5: 16 queries/wave (no spill), async double-buffered weights ----------
__global__ __launch_bounds__(512, 2) void predictor(const u16* __restrict__ h2b, const int* __restrict__ e0,
                                                    const int* __restrict__ e1, const u16* __restrict__ pW1T,
                                                    const float* __restrict__ pb1, const float* __restrict__ pW2,
                                                    const float* __restrict__ pb2, float* __restrict__ out, int Q) {
    __shared__ u16 Bs[2][64 * 256];   // 2 x 32 KB double buffer
    int tid = threadIdx.x;
    int wave = tid >> 6, lane = tid & 63, l15 = lane & 15, quad = lane >> 4;

    // async stage of 64 weight rows (phase p) into buf; swizzle folded into source address
    auto stage = [&](int p, u16* buf) {
#pragma unroll
        for (int i = 0; i < 4; i++) {
            int m = wave * 4 + i;                 // 1 KB chunk
            int nl = m * 2 + (lane >> 5);         // local n row 0..63
            int cl = lane & 31;                   // swizzled 16B slot
            int cs = cl ^ (nl & 7);               // source chunk
            const u16* g = pW1T + (long)(p * 64 + nl) * 256 + cs * 8;
            gld_lds16(g, buf + m * 512);          // lane writes at +lane*16B
        }
    };

    stage(0, Bs[0]);   // in flight under the z-gathers

    int q0 = blockIdx.x * 128;
    int q = min(q0 + wave * 16 + l15, Q - 1);
    long u = (long)e0[q] * 256, v = (long)e1[q] * 256;
    short8 za[8];
#pragma unroll
    for (int ki = 0; ki < 8; ki++) {
        uint4 a = *(const uint4*)(h2b + u + ki * 32 + quad * 8);
        uint4 b = *(const uint4*)(h2b + v + ki * 32 + quad * 8);
        uint4 z;
        z.x = pkmul(a.x, b.x);
        z.y = pkmul(a.y, b.y);
        z.z = pkmul(a.z, b.z);
        z.w = pkmul(a.w, b.w);
        za[ki] = *(short8*)&z;
    }
    floatx4 acc[16];
    floatx4 zero = {0.f, 0.f, 0.f, 0.f};
#pragma unroll
    for (int j = 0; j < 16; j++) acc[j] = zero;

#pragma unroll
    for (int p = 0; p < 4; p++) {
        if (p < 3) stage(p + 1, Bs[(p + 1) & 1]);
        if (p < 3) asm volatile("s_waitcnt vmcnt(4)" ::: "memory");
        else       asm volatile("s_waitcnt vmcnt(0)" ::: "memory");
        __builtin_amdgcn_s_barrier();             // buf[p&1] globally ready
        const u16* buf = Bs[p & 1];
#pragma unroll
        for (int ki = 0; ki < 8; ki++) {
#pragma unroll
            for (int nt = 0; nt < 4; nt++) {
                int nl = nt * 16 + l15;
                int cs = (ki * 4 + quad) ^ (nl & 7);
                short8 b = *(const short8*)(buf + nl * 256 + cs * 8);
                acc[p * 4 + nt] = __builtin_amdgcn_mfma_f32_16x16x32_bf16(za[ki], b, acc[p * 4 + nt], 0, 0, 0);
            }
        }
        if (p < 3) __builtin_amdgcn_s_barrier();  // all waves done reading buf[p&1]
    }
    // epilogue: out[q] = sigmoid( sum_col relu(acc + pb1[col]) * pW2[col] + pb2 )
    float rs[4] = {0.f, 0.f, 0.f, 0.f};
#pragma unroll
    for (int j = 0; j < 16; j++) {
        int col = (j >> 2) * 64 + (j & 3) * 16 + l15;
        float w2 = pW2[col], bb = pb1[col];
#pragma unroll
        for (int r = 0; r < 4; r++)
            rs[r] = fmaf(fmaxf(acc[j][r] + bb, 0.f), w2, rs[r]);
    }
#pragma unroll
    for (int m = 1; m < 16; m <<= 1) {
#pragma unroll
        for (int r = 0; r < 4; r++)
            rs[r] += __shfl_xor(rs[r], m, 64);
    }
    if (l15 == 0) {
        float b2v = pb2[0];
#pragma unroll
        for (int r = 0; r < 4; r++) {
            int qq = q0 + wave * 16 + quad * 4 + r;
            if (qq < Q) out[qq] = 1.0f / (1.0f + __expf(-(rs[r] + b2v)));
        }
    }
}

extern "C" void kernel_launch(void* const* d_in, const int* in_sizes, int n_in,
                              void* d_out, int out_size, void* d_ws, size_t ws_size,
                              hipStream_t stream) {
    const float* x      = (const float*)d_in[0];
    const int*   adj_row= (const int*)d_in[1];
    const int*   adj_col= (const int*)d_in[2];
    const int*   edges  = (const int*)d_in[3];
    const float* emb    = (const float*)d_in[4];
    const float* W1     = (const float*)d_in[5];
    const float* b1     = (const float*)d_in[6];
    const float* W2     = (const float*)d_in[7];
    const float* b2     = (const float*)d_in[8];
    const float* gamma  = (const float*)d_in[9];
    const float* beta   = (const float*)d_in[10];
    const float* pW1    = (const float*)d_in[11];
    const float* pb1    = (const float*)d_in[12];
    const float* pW2    = (const float*)d_in[13];
    const float* pb2    = (const float*)d_in[14];
    float* out = (float*)d_out;

    int N = in_sizes[0] / 128;
    int E = in_sizes[1];
    int Q = in_sizes[3] / 2;
    int NB = (N + 255) / 256;

    char* ws = (char*)d_ws;
    size_t off = 0;
    auto alloc = [&](size_t bytes) -> char* {
        char* p = ws + off;
        off += (bytes + 255) & ~(size_t)255;
        return p;
    };
    int*   deg_cnt = (int*)alloc((size_t)N * 4);
    int*   offs    = (int*)alloc((size_t)(N + 1) * 4);
    int*   cursor  = (int*)alloc((size_t)N * 4);
    float* dinv    = (float*)alloc((size_t)N * 4);
    int*   scol    = (int*)alloc((size_t)E * 4);
    float* sums    = (float*)alloc(512 * 4);
    float* coef    = (float*)alloc(512 * 4);
    int*   bsum    = (int*)alloc(256 * 4);
    int*   ebsum   = (int*)alloc(256 * 4);
    u16*   WT      = (u16*)alloc((size_t)3 * 65536 * 2);
    u16*   bufA    = (u16*)alloc((size_t)N * 256 * 2);
    u16*   bufB    = (u16*)alloc((size_t)N * 256 * 2);
    u16*   bufC    = (u16*)alloc((size_t)N * 256 * 2);

    hipMemsetAsync(deg_cnt, 0, (size_t)N * 4, stream);
    hipMemsetAsync(cursor, 0, (size_t)N * 4, stream);
    hipMemsetAsync(sums, 0, 512 * 4, stream);

    int eb  = (E + 255) / 256;
    int nb4 = (N * 64 + 255) / 256;
    int gb  = (N + 127) / 128;
    int ab  = (N + 7) / 8;

    count_deg<<<eb, 256, 0, stream>>>(adj_row, deg_cnt, E);
    deg_psum<<<NB, 256, 0, stream>>>(deg_cnt, bsum, N);
    scan_bsum<<<1, 256, 0, stream>>>(bsum, ebsum, NB, offs, N, E);
    write_offs<<<NB, 256, 0, stream>>>(deg_cnt, ebsum, offs, dinv, N);
    sort_edges<<<eb, 256, 0, stream>>>(adj_row, adj_col, offs, cursor, scol, E);
    prep_w<<<768, 256, 0, stream>>>(W1, W2, pW1, WT);
    concat_h0<<<nb4, 256, 0, stream>>>(emb, x, bufA, N);

    // conv1 (commuted): h1 = agg(h0) @ W1 + b1, with fused BN column stats
    aggregate2<0><<<ab, 256, 0, stream>>>(bufA, offs, scol, dinv, nullptr, bufB, N);
    gemm_big<1><<<gb, 512, 0, stream>>>(bufB, WT, b1, bufC, sums, N);
    bn_coef<<<1, 256, 0, stream>>>(sums, gamma, beta, coef, N);
    // conv2 (commuted): h2 = agg(relu(bn(h1))) @ W2 + b2, BN+ReLU fused into gather
    aggregate2<1><<<ab, 256, 0, stream>>>(bufC, offs, scol, dinv, coef, bufB, N);
    gemm_big<0><<<gb, 512, 0, stream>>>(bufB, WT + 65536, b2, bufC, nullptr, N);
    // link predictor
    predictor<<<(Q + 127) / 128, 512, 0, stream>>>(bufC, edges, edges + Q,
                                                   WT + 131072, pb1, pW2, pb2, out, Q);
}

// Round 7
// 502.515 us; speedup vs baseline: 1.0087x; 1.0087x over previous
//
#include <hip/hip_runtime.h>

typedef unsigned short u16;
typedef unsigned int u32;
typedef __attribute__((ext_vector_type(8))) short short8;
typedef __attribute__((ext_vector_type(4))) float floatx4;

// ---------- bf16 helpers ----------
__device__ __forceinline__ float b2f(u32 bits) { union { u32 u; float f; } c; c.u = bits << 16; return c.f; }
__device__ __forceinline__ float b2f_lo(u32 w) { union { u32 u; float f; } c; c.u = w << 16; return c.f; }
__device__ __forceinline__ float b2f_hi(u32 w) { union { u32 u; float f; } c; c.u = w & 0xFFFF0000u; return c.f; }
__device__ __forceinline__ u16 f2b(float f) {
    union { float f; u32 u; } c; c.f = f;
    u32 u = c.u;
    return (u16)((u + 0x7FFFu + ((u >> 16) & 1u)) >> 16);   // RNE
}
// packed bf16 mul, round-half-up (bias ~2^-16 rel)
__device__ __forceinline__ u32 pkmul(u32 a, u32 b) {
    union { u32 u; float f; } alo, ahi, blo, bhi, rlo, rhi;
    alo.u = a << 16; ahi.u = a & 0xFFFF0000u;
    blo.u = b << 16; bhi.u = b & 0xFFFF0000u;
    rlo.f = alo.f * blo.f; rhi.f = ahi.f * bhi.f;
    u32 lo = rlo.u + 0x8000u, hi = rhi.u + 0x8000u;
    return __builtin_amdgcn_perm(hi, lo, 0x07060302u);
}
// async global->LDS, 16B per lane; lds base must be wave-uniform
__device__ __forceinline__ void gld_lds16(const u16* g, u16* l) {
    __builtin_amdgcn_global_load_lds((const __attribute__((address_space(1))) u32*)g,
                                     (__attribute__((address_space(3))) u32*)l, 16, 0, 0);
}

// ---------- graph prep ----------
__global__ __launch_bounds__(256) void count_deg(const int* __restrict__ row, int* __restrict__ cnt, int E) {
    int e = blockIdx.x * 256 + threadIdx.x;
    if (e < E) atomicAdd(&cnt[row[e]], 1);
}

__global__ __launch_bounds__(256) void deg_psum(const int* __restrict__ cnt, int* __restrict__ bsum, int N) {
    __shared__ int sc[256];
    int t = threadIdx.x, i = blockIdx.x * 256 + t;
    sc[t] = (i < N) ? cnt[i] : 0;
    __syncthreads();
    for (int o = 128; o > 0; o >>= 1) {
        if (t < o) sc[t] += sc[t + o];
        __syncthreads();
    }
    if (t == 0) bsum[blockIdx.x] = sc[0];
}

__global__ __launch_bounds__(256) void scan_bsum(const int* __restrict__ bsum, int* __restrict__ ebsum,
                                                 int NB, int* __restrict__ offs, int N, int E) {
    __shared__ int sc[256];
    int t = threadIdx.x;
    int v = (t < NB) ? bsum[t] : 0;
    sc[t] = v;
    __syncthreads();
    for (int o = 1; o < 256; o <<= 1) {
        int u = (t >= o) ? sc[t - o] : 0;
        __syncthreads();
        sc[t] += u;
        __syncthreads();
    }
    if (t < NB) ebsum[t] = sc[t] - v;
    if (t == 0) offs[N] = E;
}

__global__ __launch_bounds__(256) void write_offs(const int* __restrict__ cnt, const int* __restrict__ ebsum,
                                                  int* __restrict__ offs, float* __restrict__ dinv, int N) {
    __shared__ int sc[256];
    int t = threadIdx.x, i = blockIdx.x * 256 + t;
    int v = (i < N) ? cnt[i] : 0;
    sc[t] = v;
    __syncthreads();
    for (int o = 1; o < 256; o <<= 1) {
        int u = (t >= o) ? sc[t - o] : 0;
        __syncthreads();
        sc[t] += u;
        __syncthreads();
    }
    if (i < N) {
        offs[i] = ebsum[blockIdx.x] + sc[t] - v;
        dinv[i] = rsqrtf((float)v + 1.0f);
    }
}

__global__ __launch_bounds__(256) void sort_edges(const int* __restrict__ row, const int* __restrict__ col,
                                                  const int* __restrict__ offs, int* __restrict__ cursor,
                                                  int* __restrict__ scol, int E) {
    int e = blockIdx.x * 256 + threadIdx.x;
    if (e < E) {
        int r = row[e];
        int p = offs[r] + atomicAdd(&cursor[r], 1);
        scol[p] = col[e];
    }
}

// ---------- weight prep: WT[which][n][k] = bf16(W[k][n]) ----------
__global__ __launch_bounds__(256) void prep_w(const float* __restrict__ W1, const float* __restrict__ W2,
                                              const float* __restrict__ pW1, u16* __restrict__ WT) {
    int tid = blockIdx.x * 256 + threadIdx.x;
    int which = tid >> 16, id = tid & 65535;
    int n = id >> 8, k = id & 255;
    const float* W = (which == 0) ? W1 : ((which == 1) ? W2 : pW1);
    WT[tid] = f2b(W[k * 256 + n]);
}

// ---------- h0 = bf16(concat(emb, x)) ----------
__global__ __launch_bounds__(256) void concat_h0(const float* __restrict__ emb, const float* __restrict__ x,
                                                 u16* __restrict__ h0b, int N) {
    int t = blockIdx.x * 256 + threadIdx.x;
    long base = (long)t * 4;
    if (base >= (long)N * 256) return;
    int i = (int)(base >> 8), k = (int)(base & 255);
    const float* src = (k < 128) ? (emb + (long)i * 128 + k) : (x + (long)i * 128 + (k - 128));
    float4 v = *(const float4*)src;
    ushort4 o;
    o.x = f2b(v.x); o.y = f2b(v.y); o.z = f2b(v.z); o.w = f2b(v.w);
    *(ushort4*)(h0b + base) = o;
}

// ---------- aggregation: 1 node per half-wave (32 lanes x uint4 = full 512B row) ----------
// FUSED_BN: input transform x' = relu(x*scale + shift) applied to every gathered element
template <int FUSED_BN>
__global__ __launch_bounds__(256) void aggregate2(const u16* __restrict__ h, const int* __restrict__ offs,
                                                  const int* __restrict__ scol, const float* __restrict__ dinv,
                                                  const float* __restrict__ coef, u16* __restrict__ out, int N) {
    int hw = threadIdx.x >> 5, lane = threadIdx.x & 31;
    int node = blockIdx.x * 8 + hw;
    if (node >= N) return;
    float sc[8], sh[8];
    if (FUSED_BN) {
#pragma unroll
        for (int i = 0; i < 8; i++) { sc[i] = coef[lane * 8 + i]; sh[i] = coef[256 + lane * 8 + i]; }
    }
    float a[8];
#pragma unroll
    for (int i = 0; i < 8; i++) a[i] = 0.f;

    auto rowAcc = [&](uint4 u, float d) {
        float f[8];
        f[0] = b2f_lo(u.x); f[1] = b2f_hi(u.x);
        f[2] = b2f_lo(u.y); f[3] = b2f_hi(u.y);
        f[4] = b2f_lo(u.z); f[5] = b2f_hi(u.z);
        f[6] = b2f_lo(u.w); f[7] = b2f_hi(u.w);
#pragma unroll
        for (int i = 0; i < 8; i++) {
            float v = f[i];
            if (FUSED_BN) v = fmaxf(fmaf(v, sc[i], sh[i]), 0.f);
            a[i] = fmaf(v, d, a[i]);
        }
    };
    int beg = offs[node], end = offs[node + 1];
    int j = beg;
    for (; j + 3 < end; j += 4) {
        int c0 = scol[j], c1 = scol[j + 1], c2 = scol[j + 2], c3 = scol[j + 3];
        float d0 = dinv[c0], d1 = dinv[c1], d2 = dinv[c2], d3 = dinv[c3];
        uint4 v0 = *(const uint4*)(h + (long)c0 * 256 + lane * 8);
        uint4 v1 = *(const uint4*)(h + (long)c1 * 256 + lane * 8);
        uint4 v2 = *(const uint4*)(h + (long)c2 * 256 + lane * 8);
        uint4 v3 = *(const uint4*)(h + (long)c3 * 256 + lane * 8);
        rowAcc(v0, d0); rowAcc(v1, d1); rowAcc(v2, d2); rowAcc(v3, d3);
    }
    for (; j < end; j++) {
        int c0 = scol[j];
        float d0 = dinv[c0];
        uint4 v0 = *(const uint4*)(h + (long)c0 * 256 + lane * 8);
        rowAcc(v0, d0);
    }
    float di = dinv[node];
    {
        uint4 u = *(const uint4*)(h + (long)node * 256 + lane * 8);
        rowAcc(u, di);   // self term with weight di (total = sum + di*self)
    }
    u16 ob[8];
#pragma unroll
    for (int i = 0; i < 8; i++) ob[i] = f2b(di * a[i]);
    ushort4 o0, o1;
    o0.x = ob[0]; o0.y = ob[1]; o0.z = ob[2]; o0.w = ob[3];
    o1.x = ob[4]; o1.y = ob[5]; o1.z = ob[6]; o1.w = ob[7];
    *(ushort4*)(out + (long)node * 256 + lane * 8) = o0;
    *(ushort4*)(out + (long)node * 256 + lane * 8 + 4) = o1;
}

// ---------- GEMM v3: C_bf16[M][256] = A_bf16[M][256] @ B + bias ----------
// 512 thr, 256 rows/block (196 blocks). B staged once per block in 2 n-phases of 64 KB.
// Per (phase, row-group): acc[8] only (32 AGPR). Epilogue transposes through padded LDS tile
// so every global C store is a full 64B sector (R6 lesson: 2B scattered stores -> 1.4x HBM
// write amplification + RMW fetches; dur tracked hbm_bytes at ~300-400 GB/s).
template <int STATS>
__global__ __launch_bounds__(512, 2) void gemm_big(const u16* __restrict__ A, const u16* __restrict__ BT,
                                                   const float* __restrict__ bias, u16* __restrict__ C,
                                                   float* __restrict__ sums, int M) {
    __shared__ u16 Bs[128 * 256];    // 64 KB: one n-phase (128 cols) of BT
    __shared__ u16 Cs[128 * 136];    // 34 KB transpose tile, +8 pad per row (2-way banks)
    int tid = threadIdx.x;
    int wave = tid >> 6, lane = tid & 63, l15 = lane & 15, quad = lane >> 4;
    int rowB = blockIdx.x * 256;

    // A fragments for both 128-row groups, loaded once (64 VGPR)
    short8 za[2][8];
#pragma unroll
    for (int g = 0; g < 2; g++) {
        long arow = min(rowB + g * 128 + wave * 16 + l15, M - 1);
#pragma unroll
        for (int ki = 0; ki < 8; ki++)
            za[g][ki] = *(const short8*)(A + arow * 256 + ki * 32 + quad * 8);
    }

#pragma unroll
    for (int p = 0; p < 2; p++) {
        if (p) __syncthreads();   // everyone done with Bs/Cs of previous phase
        {   // stage 128 n-rows of BT, 16B chunks xor-swizzled by (n&7)
            int nl = tid >> 2, cg = (tid & 3) * 8;
            const uint4* src = (const uint4*)(BT + (long)(p * 128 + nl) * 256);
#pragma unroll
            for (int c8 = 0; c8 < 8; c8++) {
                int c = cg + c8;
                int cs = c ^ (nl & 7);
                *(uint4*)(Bs + nl * 256 + cs * 8) = src[c];
            }
        }
        __syncthreads();
#pragma unroll
        for (int g = 0; g < 2; g++) {
            floatx4 acc[8];
            floatx4 zero = {0.f, 0.f, 0.f, 0.f};
#pragma unroll
            for (int j = 0; j < 8; j++) acc[j] = zero;
#pragma unroll
            for (int ki = 0; ki < 8; ki++) {
#pragma unroll
                for (int nt = 0; nt < 8; nt++) {
                    int nl = nt * 16 + l15;
                    int cs = (ki * 4 + quad) ^ (l15 & 7);
                    short8 b = *(const short8*)(Bs + nl * 256 + cs * 8);
                    acc[nt] = __builtin_amdgcn_mfma_f32_16x16x32_bf16(za[g][ki], b, acc[nt], 0, 0, 0);
                }
            }
            // ---- epilogue: bias, stats, LDS transpose, coalesced store ----
            if (g || p) __syncthreads();   // previous Cs fully read
#pragma unroll
            for (int j = 0; j < 8; j++) {
                int col = p * 128 + j * 16 + l15;
                float bv = bias[col];
                float s = 0.f, s2 = 0.f;
#pragma unroll
                for (int r = 0; r < 4; r++) {
                    int row = rowB + g * 128 + wave * 16 + quad * 4 + r;
                    float val = acc[j][r] + bv;
                    Cs[(wave * 16 + quad * 4 + r) * 136 + j * 16 + l15] = f2b(val);
                    if (STATS && row < M) { s += val; s2 = fmaf(val, val, s2); }
                }
                if (STATS) {
                    s += __shfl_xor(s, 16, 64); s += __shfl_xor(s, 32, 64);
                    s2 += __shfl_xor(s2, 16, 64); s2 += __shfl_xor(s2, 32, 64);
                    if (quad == 0) {
                        unsafeAtomicAdd(&sums[col], s);
                        unsafeAtomicAdd(&sums[256 + col], s2);
                    }
                }
            }
            __syncthreads();   // Cs tile complete
            {   // thread t: row t>>2, 64B chunk t&3 -> full-sector global store
                int row = tid >> 2, ch = tid & 3;
                int grow = rowB + g * 128 + row;
                if (grow < M) {
                    const u16* src = Cs + row * 136 + ch * 32;
                    u16* dst = C + (long)grow * 256 + p * 128 + ch * 32;
                    uint4 v0 = *(const uint4*)(src);
                    uint4 v1 = *(const uint4*)(src + 8);
                    uint4 v2 = *(const uint4*)(src + 16);
                    uint4 v3 = *(const uint4*)(src + 24);
                    *(uint4*)(dst) = v0;
                    *(uint4*)(dst + 8) = v1;
                    *(uint4*)(dst + 16) = v2;
                    *(uint4*)(dst + 24) = v3;
                }
            }
        }
    }
}

// ---------- BN coefficients: scale/shift per column ----------
__global__ __launch_bounds__(256) void bn_coef(const float* __restrict__ sums, const float* __restrict__ gamma,
                                               const float* __restrict__ beta, float* __restrict__ coef, int N) {
    int c = threadIdx.x;
    float invN = 1.0f / (float)N;
    float mean = sums[c] * invN;
    float var = sums[256 + c] * invN - mean * mean;
    float s = gamma[c] * rsqrtf(var + 1e-5f);
    coef[c] = s;
    coef[256 + c] = beta[c] - mean * s;
}

// ---------- predictor v5: 16 queries/wave, async double-buffered weights ----------
__global__ __launch_bounds__(512, 2) void predictor(const u16* __restrict__ h2b, const int* __restrict__ e0,
                                                    const int* __restrict__ e1, const u16* __restrict__ pW1T,
                                                    const float* __restrict__ pb1, const float* __restrict__ pW2,
                                                    const float* __restrict__ pb2, float* __restrict__ out, int Q) {
    __shared__ u16 Bs[2][64 * 256];   // 2 x 32 KB double buffer
    int tid = threadIdx.x;
    int wave = tid >> 6, lane = tid & 63, l15 = lane & 15, quad = lane >> 4;

    // async stage of 64 weight rows (phase p) into buf; swizzle folded into source address
    auto stage = [&](int p, u16* buf) {
#pragma unroll
        for (int i = 0; i < 4; i++) {
            int m = wave * 4 + i;                 // 1 KB chunk
            int nl = m * 2 + (lane >> 5);         // local n row 0..63
            int cl = lane & 31;                   // swizzled 16B slot
            int cs = cl ^ (nl & 7);               // source chunk
            const u16* g = pW1T + (long)(p * 64 + nl) * 256 + cs * 8;
            gld_lds16(g, buf + m * 512);          // lane writes at +lane*16B
        }
    };

    stage(0, Bs[0]);   // in flight under the z-gathers

    int q0 = blockIdx.x * 128;
    int q = min(q0 + wave * 16 + l15, Q - 1);
    long u = (long)e0[q] * 256, v = (long)e1[q] * 256;
    short8 za[8];
#pragma unroll
    for (int ki = 0; ki < 8; ki++) {
        uint4 a = *(const uint4*)(h2b + u + ki * 32 + quad * 8);
        uint4 b = *(const uint4*)(h2b + v + ki * 32 + quad * 8);
        uint4 z;
        z.x = pkmul(a.x, b.x);
        z.y = pkmul(a.y, b.y);
        z.z = pkmul(a.z, b.z);
        z.w = pkmul(a.w, b.w);
        za[ki] = *(short8*)&z;
    }
    floatx4 acc[16];
    floatx4 zero = {0.f, 0.f, 0.f, 0.f};
#pragma unroll
    for (int j = 0; j < 16; j++) acc[j] = zero;

#pragma unroll
    for (int p = 0; p < 4; p++) {
        if (p < 3) stage(p + 1, Bs[(p + 1) & 1]);
        if (p < 3) asm volatile("s_waitcnt vmcnt(4)" ::: "memory");
        else       asm volatile("s_waitcnt vmcnt(0)" ::: "memory");
        __builtin_amdgcn_s_barrier();             // buf[p&1] globally ready
        const u16* buf = Bs[p & 1];
#pragma unroll
        for (int ki = 0; ki < 8; ki++) {
#pragma unroll
            for (int nt = 0; nt < 4; nt++) {
                int nl = nt * 16 + l15;
                int cs = (ki * 4 + quad) ^ (nl & 7);
                short8 b = *(const short8*)(buf + nl * 256 + cs * 8);
                acc[p * 4 + nt] = __builtin_amdgcn_mfma_f32_16x16x32_bf16(za[ki], b, acc[p * 4 + nt], 0, 0, 0);
            }
        }
        if (p < 3) __builtin_amdgcn_s_barrier();  // all waves done reading buf[p&1]
    }
    // epilogue: out[q] = sigmoid( sum_col relu(acc + pb1[col]) * pW2[col] + pb2 )
    float rs[4] = {0.f, 0.f, 0.f, 0.f};
#pragma unroll
    for (int j = 0; j < 16; j++) {
        int col = (j >> 2) * 64 + (j & 3) * 16 + l15;
        float w2 = pW2[col], bb = pb1[col];
#pragma unroll
        for (int r = 0; r < 4; r++)
            rs[r] = fmaf(fmaxf(acc[j][r] + bb, 0.f), w2, rs[r]);
    }
#pragma unroll
    for (int m = 1; m < 16; m <<= 1) {
#pragma unroll
        for (int r = 0; r < 4; r++)
            rs[r] += __shfl_xor(rs[r], m, 64);
    }
    if (l15 == 0) {
        float b2v = pb2[0];
#pragma unroll
        for (int r = 0; r < 4; r++) {
            int qq = q0 + wave * 16 + quad * 4 + r;
            if (qq < Q) out[qq] = 1.0f / (1.0f + __expf(-(rs[r] + b2v)));
        }
    }
}

extern "C" void kernel_launch(void* const* d_in, const int* in_sizes, int n_in,
                              void* d_out, int out_size, void* d_ws, size_t ws_size,
                              hipStream_t stream) {
    const float* x      = (const float*)d_in[0];
    const int*   adj_row= (const int*)d_in[1];
    const int*   adj_col= (const int*)d_in[2];
    const int*   edges  = (const int*)d_in[3];
    const float* emb    = (const float*)d_in[4];
    const float* W1     = (const float*)d_in[5];
    const float* b1     = (const float*)d_in[6];
    const float* W2     = (const float*)d_in[7];
    const float* b2     = (const float*)d_in[8];
    const float* gamma  = (const float*)d_in[9];
    const float* beta   = (const float*)d_in[10];
    const float* pW1    = (const float*)d_in[11];
    const float* pb1    = (const float*)d_in[12];
    const float* pW2    = (const float*)d_in[13];
    const float* pb2    = (const float*)d_in[14];
    float* out = (float*)d_out;

    int N = in_sizes[0] / 128;
    int E = in_sizes[1];
    int Q = in_sizes[3] / 2;
    int NB = (N + 255) / 256;

    char* ws = (char*)d_ws;
    size_t off = 0;
    auto alloc = [&](size_t bytes) -> char* {
        char* p = ws + off;
        off += (bytes + 255) & ~(size_t)255;
        return p;
    };
    int*   deg_cnt = (int*)alloc((size_t)N * 4);
    int*   offs    = (int*)alloc((size_t)(N + 1) * 4);
    int*   cursor  = (int*)alloc((size_t)N * 4);
    float* dinv    = (float*)alloc((size_t)N * 4);
    int*   scol    = (int*)alloc((size_t)E * 4);
    float* sums    = (float*)alloc(512 * 4);
    float* coef    = (float*)alloc(512 * 4);
    int*   bsum    = (int*)alloc(256 * 4);
    int*   ebsum   = (int*)alloc(256 * 4);
    u16*   WT      = (u16*)alloc((size_t)3 * 65536 * 2);
    u16*   bufA    = (u16*)alloc((size_t)N * 256 * 2);
    u16*   bufB    = (u16*)alloc((size_t)N * 256 * 2);
    u16*   bufC    = (u16*)alloc((size_t)N * 256 * 2);

    hipMemsetAsync(deg_cnt, 0, (size_t)N * 4, stream);
    hipMemsetAsync(cursor, 0, (size_t)N * 4, stream);
    hipMemsetAsync(sums, 0, 512 * 4, stream);

    int eb  = (E + 255) / 256;
    int nb4 = (N * 64 + 255) / 256;
    int gb  = (N + 255) / 256;
    int ab  = (N + 7) / 8;

    count_deg<<<eb, 256, 0, stream>>>(adj_row, deg_cnt, E);
    deg_psum<<<NB, 256, 0, stream>>>(deg_cnt, bsum, N);
    scan_bsum<<<1, 256, 0, stream>>>(bsum, ebsum, NB, offs, N, E);
    write_offs<<<NB, 256, 0, stream>>>(deg_cnt, ebsum, offs, dinv, N);
    sort_edges<<<eb, 256, 0, stream>>>(adj_row, adj_col, offs, cursor, scol, E);
    prep_w<<<768, 256, 0, stream>>>(W1, W2, pW1, WT);
    concat_h0<<<nb4, 256, 0, stream>>>(emb, x, bufA, N);

    // conv1 (commuted): h1 = agg(h0) @ W1 + b1, with fused BN column stats
    aggregate2<0><<<ab, 256, 0, stream>>>(bufA, offs, scol, dinv, nullptr, bufB, N);
    gemm_big<1><<<gb, 512, 0, stream>>>(bufB, WT, b1, bufC, sums, N);
    bn_coef<<<1, 256, 0, stream>>>(sums, gamma, beta, coef, N);
    // conv2 (commuted): h2 = agg(relu(bn(h1))) @ W2 + b2, BN+ReLU fused into gather
    aggregate2<1><<<ab, 256, 0, stream>>>(bufC, offs, scol, dinv, coef, bufB, N);
    gemm_big<0><<<gb, 512, 0, stream>>>(bufB, WT + 65536, b2, bufC, nullptr, N);
    // link predictor
    predictor<<<(Q + 127) / 128, 512, 0, stream>>>(bufC, edges, edges + Q,
                                                   WT + 131072, pb1, pW2, pb2, out, Q);
}

// Round 8
// 392.296 us; speedup vs baseline: 1.2922x; 1.2810x over previous
//
#include <hip/hip_runtime.h>

typedef unsigned short u16;
typedef unsigned int u32;
typedef __attribute__((ext_vector_type(8))) short short8;
typedef __attribute__((ext_vector_type(4))) float floatx4;

// ---------- bf16 helpers ----------
__device__ __forceinline__ float b2f(u32 bits) { union { u32 u; float f; } c; c.u = bits << 16; return c.f; }
__device__ __forceinline__ float b2f_lo(u32 w) { union { u32 u; float f; } c; c.u = w << 16; return c.f; }
__device__ __forceinline__ float b2f_hi(u32 w) { union { u32 u; float f; } c; c.u = w & 0xFFFF0000u; return c.f; }
__device__ __forceinline__ u16 f2b(float f) {
    union { float f; u32 u; } c; c.f = f;
    u32 u = c.u;
    return (u16)((u + 0x7FFFu + ((u >> 16) & 1u)) >> 16);   // RNE
}
// packed bf16 mul, round-half-up (bias ~2^-16 rel)
__device__ __forceinline__ u32 pkmul(u32 a, u32 b) {
    union { u32 u; float f; } alo, ahi, blo, bhi, rlo, rhi;
    alo.u = a << 16; ahi.u = a & 0xFFFF0000u;
    blo.u = b << 16; bhi.u = b & 0xFFFF0000u;
    rlo.f = alo.f * blo.f; rhi.f = ahi.f * bhi.f;
    u32 lo = rlo.u + 0x8000u, hi = rhi.u + 0x8000u;
    return __builtin_amdgcn_perm(hi, lo, 0x07060302u);
}
// async global->LDS, 16B per lane; lds base must be wave-uniform
__device__ __forceinline__ void gld_lds16(const u16* g, u16* l) {
    __builtin_amdgcn_global_load_lds((const __attribute__((address_space(1))) u32*)g,
                                     (__attribute__((address_space(3))) u32*)l, 16, 0, 0);
}

// ---------- graph prep ----------
__global__ __launch_bounds__(256) void count_deg(const int* __restrict__ row, int* __restrict__ cnt, int E) {
    int e = blockIdx.x * 256 + threadIdx.x;
    if (e < E) atomicAdd(&cnt[row[e]], 1);
}

__global__ __launch_bounds__(256) void deg_psum(const int* __restrict__ cnt, int* __restrict__ bsum, int N) {
    __shared__ int sc[256];
    int t = threadIdx.x, i = blockIdx.x * 256 + t;
    sc[t] = (i < N) ? cnt[i] : 0;
    __syncthreads();
    for (int o = 128; o > 0; o >>= 1) {
        if (t < o) sc[t] += sc[t + o];
        __syncthreads();
    }
    if (t == 0) bsum[blockIdx.x] = sc[0];
}

__global__ __launch_bounds__(256) void scan_bsum(const int* __restrict__ bsum, int* __restrict__ ebsum,
                                                 int NB, int* __restrict__ offs, int N, int E) {
    __shared__ int sc[256];
    int t = threadIdx.x;
    int v = (t < NB) ? bsum[t] : 0;
    sc[t] = v;
    __syncthreads();
    for (int o = 1; o < 256; o <<= 1) {
        int u = (t >= o) ? sc[t - o] : 0;
        __syncthreads();
        sc[t] += u;
        __syncthreads();
    }
    if (t < NB) ebsum[t] = sc[t] - v;
    if (t == 0) offs[N] = E;
}

__global__ __launch_bounds__(256) void write_offs(const int* __restrict__ cnt, const int* __restrict__ ebsum,
                                                  int* __restrict__ offs, float* __restrict__ dinv, int N) {
    __shared__ int sc[256];
    int t = threadIdx.x, i = blockIdx.x * 256 + t;
    int v = (i < N) ? cnt[i] : 0;
    sc[t] = v;
    __syncthreads();
    for (int o = 1; o < 256; o <<= 1) {
        int u = (t >= o) ? sc[t - o] : 0;
        __syncthreads();
        sc[t] += u;
        __syncthreads();
    }
    if (i < N) {
        offs[i] = ebsum[blockIdx.x] + sc[t] - v;
        dinv[i] = rsqrtf((float)v + 1.0f);
    }
}

__global__ __launch_bounds__(256) void sort_edges(const int* __restrict__ row, const int* __restrict__ col,
                                                  const int* __restrict__ offs, int* __restrict__ cursor,
                                                  int* __restrict__ scol, int E) {
    int e = blockIdx.x * 256 + threadIdx.x;
    if (e < E) {
        int r = row[e];
        int p = offs[r] + atomicAdd(&cursor[r], 1);
        scol[p] = col[e];
    }
}

// ---------- weight prep: WT[which][n][k] = bf16(W[k][n]) ----------
__global__ __launch_bounds__(256) void prep_w(const float* __restrict__ W1, const float* __restrict__ W2,
                                              const float* __restrict__ pW1, u16* __restrict__ WT) {
    int tid = blockIdx.x * 256 + threadIdx.x;
    int which = tid >> 16, id = tid & 65535;
    int n = id >> 8, k = id & 255;
    const float* W = (which == 0) ? W1 : ((which == 1) ? W2 : pW1);
    WT[tid] = f2b(W[k * 256 + n]);
}

// ---------- h0 = bf16(concat(emb, x)) ----------
__global__ __launch_bounds__(256) void concat_h0(const float* __restrict__ emb, const float* __restrict__ x,
                                                 u16* __restrict__ h0b, int N) {
    int t = blockIdx.x * 256 + threadIdx.x;
    long base = (long)t * 4;
    if (base >= (long)N * 256) return;
    int i = (int)(base >> 8), k = (int)(base & 255);
    const float* src = (k < 128) ? (emb + (long)i * 128 + k) : (x + (long)i * 128 + (k - 128));
    float4 v = *(const float4*)src;
    ushort4 o;
    o.x = f2b(v.x); o.y = f2b(v.y); o.z = f2b(v.z); o.w = f2b(v.w);
    *(ushort4*)(h0b + base) = o;
}

// ---------- aggregation: 1 node per half-wave (32 lanes x uint4 = full 512B row) ----------
// FUSED_BN: input transform x' = relu(x*scale + shift) applied to every gathered element
template <int FUSED_BN>
__global__ __launch_bounds__(256) void aggregate2(const u16* __restrict__ h, const int* __restrict__ offs,
                                                  const int* __restrict__ scol, const float* __restrict__ dinv,
                                                  const float* __restrict__ coef, u16* __restrict__ out, int N) {
    int hw = threadIdx.x >> 5, lane = threadIdx.x & 31;
    int node = blockIdx.x * 8 + hw;
    if (node >= N) return;
    float sc[8], sh[8];
    if (FUSED_BN) {
#pragma unroll
        for (int i = 0; i < 8; i++) { sc[i] = coef[lane * 8 + i]; sh[i] = coef[256 + lane * 8 + i]; }
    }
    float a[8];
#pragma unroll
    for (int i = 0; i < 8; i++) a[i] = 0.f;

    auto rowAcc = [&](uint4 u, float d) {
        float f[8];
        f[0] = b2f_lo(u.x); f[1] = b2f_hi(u.x);
        f[2] = b2f_lo(u.y); f[3] = b2f_hi(u.y);
        f[4] = b2f_lo(u.z); f[5] = b2f_hi(u.z);
        f[6] = b2f_lo(u.w); f[7] = b2f_hi(u.w);
#pragma unroll
        for (int i = 0; i < 8; i++) {
            float v = f[i];
            if (FUSED_BN) v = fmaxf(fmaf(v, sc[i], sh[i]), 0.f);
            a[i] = fmaf(v, d, a[i]);
        }
    };
    int beg = offs[node], end = offs[node + 1];
    int j = beg;
    for (; j + 3 < end; j += 4) {
        int c0 = scol[j], c1 = scol[j + 1], c2 = scol[j + 2], c3 = scol[j + 3];
        float d0 = dinv[c0], d1 = dinv[c1], d2 = dinv[c2], d3 = dinv[c3];
        uint4 v0 = *(const uint4*)(h + (long)c0 * 256 + lane * 8);
        uint4 v1 = *(const uint4*)(h + (long)c1 * 256 + lane * 8);
        uint4 v2 = *(const uint4*)(h + (long)c2 * 256 + lane * 8);
        uint4 v3 = *(const uint4*)(h + (long)c3 * 256 + lane * 8);
        rowAcc(v0, d0); rowAcc(v1, d1); rowAcc(v2, d2); rowAcc(v3, d3);
    }
    for (; j < end; j++) {
        int c0 = scol[j];
        float d0 = dinv[c0];
        uint4 v0 = *(const uint4*)(h + (long)c0 * 256 + lane * 8);
        rowAcc(v0, d0);
    }
    float di = dinv[node];
    {
        uint4 u = *(const uint4*)(h + (long)node * 256 + lane * 8);
        rowAcc(u, di);   // self term with weight di (total = sum + di*self)
    }
    u16 ob[8];
#pragma unroll
    for (int i = 0; i < 8; i++) ob[i] = f2b(di * a[i]);
    ushort4 o0, o1;
    o0.x = ob[0]; o0.y = ob[1]; o0.z = ob[2]; o0.w = ob[3];
    o1.x = ob[4]; o1.y = ob[5]; o1.z = ob[6]; o1.w = ob[7];
    *(ushort4*)(out + (long)node * 256 + lane * 8) = o0;
    *(ushort4*)(out + (long)node * 256 + lane * 8 + 4) = o1;
}

// ---------- GEMM v4: faithful port of the HW-verified m93/m97 ladder structure ----------
// 256 thr / 4 waves, 128x128 tile, BK=64, BOTH operands staged to LDS each K-step,
// plain ds_write_b128/ds_read_b128 (no swizzle), 2 barriers per K-step, acc[4][4],
// epilogue fully outside the K-loop. Grid (rowTiles, 2 colTiles).
// (R4-R7 lesson: bespoke register-A + xor-swizzle + in-loop epilogue structure carried a
// ~160us all-pipes-idle stall envelope, insensitive to blocks/occupancy/VGPR/writes.)
template <int STATS>
__global__ __launch_bounds__(256) void gemm_big(const u16* __restrict__ A, const u16* __restrict__ BT,
                                                const float* __restrict__ bias, u16* __restrict__ C,
                                                float* __restrict__ sums, int M) {
    __shared__ u16 As[128 * 64];   // 16 KB
    __shared__ u16 Bs[128 * 64];   // 16 KB
    __shared__ u16 Cs[64 * 136];   // 17 KB transpose tile (+8 pad)
    int tid = threadIdx.x;
    int wave = tid >> 6, lane = tid & 63, l15 = lane & 15, quad = lane >> 4;
    int row0 = blockIdx.x * 128;
    int col0 = blockIdx.y * 128;
    int wr = (wave & 1) * 64, wc = (wave >> 1) * 64;

    floatx4 acc[4][4];
    floatx4 zero = {0.f, 0.f, 0.f, 0.f};
#pragma unroll
    for (int mi = 0; mi < 4; mi++)
#pragma unroll
        for (int ni = 0; ni < 4; ni++) acc[mi][ni] = zero;

    for (int k0 = 0; k0 < 256; k0 += 64) {
#pragma unroll
        for (int c = 0; c < 4; c++) {          // stage A and B tiles: 1024 16B-chunks each
            int id = c * 256 + tid;
            int r = id >> 3, kc = id & 7;
            *(uint4*)(As + r * 64 + kc * 8) =
                *(const uint4*)(A + (long)min(row0 + r, M - 1) * 256 + k0 + kc * 8);
            *(uint4*)(Bs + r * 64 + kc * 8) =
                *(const uint4*)(BT + (long)(col0 + r) * 256 + k0 + kc * 8);
        }
        __syncthreads();
#pragma unroll
        for (int kk = 0; kk < 64; kk += 32) {
            short8 am[4], bn[4];
#pragma unroll
            for (int i = 0; i < 4; i++) {
                am[i] = *(const short8*)(As + (wr + i * 16 + l15) * 64 + kk + quad * 8);
                bn[i] = *(const short8*)(Bs + (wc + i * 16 + l15) * 64 + kk + quad * 8);
            }
#pragma unroll
            for (int mi = 0; mi < 4; mi++)
#pragma unroll
                for (int ni = 0; ni < 4; ni++)
                    acc[mi][ni] = __builtin_amdgcn_mfma_f32_16x16x32_bf16(am[mi], bn[ni], acc[mi][ni], 0, 0, 0);
        }
        __syncthreads();
    }

    // ---- epilogue: bias (+ BN column stats), then coalesced store via Cs transpose ----
    float s[4], s2[4];
    if (STATS) {
#pragma unroll
        for (int ni = 0; ni < 4; ni++) { s[ni] = 0.f; s2[ni] = 0.f; }
    }
#pragma unroll
    for (int ni = 0; ni < 4; ni++) {
        int gcol = col0 + wc + ni * 16 + l15;
        float bv = bias[gcol];
#pragma unroll
        for (int mi = 0; mi < 4; mi++)
#pragma unroll
            for (int r = 0; r < 4; r++) {
                float v = acc[mi][ni][r] + bv;
                acc[mi][ni][r] = v;
                if (STATS) {
                    int grow = row0 + wr + mi * 16 + quad * 4 + r;
                    if (grow < M) { s[ni] += v; s2[ni] = fmaf(v, v, s2[ni]); }
                }
            }
    }
    if (STATS) {
#pragma unroll
        for (int ni = 0; ni < 4; ni++) {
            float a = s[ni], b = s2[ni];
            a += __shfl_xor(a, 16, 64); a += __shfl_xor(a, 32, 64);
            b += __shfl_xor(b, 16, 64); b += __shfl_xor(b, 32, 64);
            if (quad == 0) {
                int gcol = col0 + wc + ni * 16 + l15;
                unsafeAtomicAdd(&sums[gcol], a);
                unsafeAtomicAdd(&sums[256 + gcol], b);
            }
        }
    }
    // two 64-row halves: waves with (wave&1)==h own rows h*64..h*64+63
#pragma unroll
    for (int h = 0; h < 2; h++) {
        __syncthreads();
        if ((wave & 1) == h) {
#pragma unroll
            for (int mi = 0; mi < 4; mi++)
#pragma unroll
                for (int ni = 0; ni < 4; ni++)
#pragma unroll
                    for (int r = 0; r < 4; r++)
                        Cs[(mi * 16 + quad * 4 + r) * 136 + wc + ni * 16 + l15] = f2b(acc[mi][ni][r]);
        }
        __syncthreads();
        {   // thread t: row t>>2, 64B chunk t&3 -> full-sector stores
            int r = tid >> 2, ch = tid & 3;
            int grow = row0 + h * 64 + r;
            if (grow < M) {
                const u16* src = Cs + r * 136 + ch * 32;
                u16* dst = C + (long)grow * 256 + col0 + ch * 32;
                uint4 v0 = *(const uint4*)(src);
                uint4 v1 = *(const uint4*)(src + 8);
                uint4 v2 = *(const uint4*)(src + 16);
                uint4 v3 = *(const uint4*)(src + 24);
                *(uint4*)(dst) = v0;
                *(uint4*)(dst + 8) = v1;
                *(uint4*)(dst + 16) = v2;
                *(uint4*)(dst + 24) = v3;
            }
        }
    }
}

// ---------- BN coefficients: scale/shift per column ----------
__global__ __launch_bounds__(256) void bn_coef(const float* __restrict__ sums, const float* __restrict__ gamma,
                                               const float* __restrict__ beta, float* __restrict__ coef, int N) {
    int c = threadIdx.x;
    float invN = 1.0f / (float)N;
    float mean = sums[c] * invN;
    float var = sums[256 + c] * invN - mean * mean;
    float s = gamma[c] * rsqrtf(var + 1e-5f);
    coef[c] = s;
    coef[256 + c] = beta[c] - mean * s;
}

// ---------- predictor v5: 16 queries/wave, async double-buffered weights ----------
__global__ __launch_bounds__(512, 2) void predictor(const u16* __restrict__ h2b, const int* __restrict__ e0,
                                                    const int* __restrict__ e1, const u16* __restrict__ pW1T,
                                                    const float* __restrict__ pb1, const float* __restrict__ pW2,
                                                    const float* __restrict__ pb2, float* __restrict__ out, int Q) {
    __shared__ u16 Bs[2][64 * 256];   // 2 x 32 KB double buffer
    int tid = threadIdx.x;
    int wave = tid >> 6, lane = tid & 63, l15 = lane & 15, quad = lane >> 4;

    // async stage of 64 weight rows (phase p) into buf; swizzle folded into source address
    auto stage = [&](int p, u16* buf) {
#pragma unroll
        for (int i = 0; i < 4; i++) {
            int m = wave * 4 + i;                 // 1 KB chunk
            int nl = m * 2 + (lane >> 5);         // local n row 0..63
            int cl = lane & 31;                   // swizzled 16B slot
            int cs = cl ^ (nl & 7);               // source chunk
            const u16* g = pW1T + (long)(p * 64 + nl) * 256 + cs * 8;
            gld_lds16(g, buf + m * 512);          // lane writes at +lane*16B
        }
    };

    stage(0, Bs[0]);   // in flight under the z-gathers

    int q0 = blockIdx.x * 128;
    int q = min(q0 + wave * 16 + l15, Q - 1);
    long u = (long)e0[q] * 256, v = (long)e1[q] * 256;
    short8 za[8];
#pragma unroll
    for (int ki = 0; ki < 8; ki++) {
        uint4 a = *(const uint4*)(h2b + u + ki * 32 + quad * 8);
        uint4 b = *(const uint4*)(h2b + v + ki * 32 + quad * 8);
        uint4 z;
        z.x = pkmul(a.x, b.x);
        z.y = pkmul(a.y, b.y);
        z.z = pkmul(a.z, b.z);
        z.w = pkmul(a.w, b.w);
        za[ki] = *(short8*)&z;
    }
    floatx4 acc[16];
    floatx4 zero = {0.f, 0.f, 0.f, 0.f};
#pragma unroll
    for (int j = 0; j < 16; j++) acc[j] = zero;

#pragma unroll
    for (int p = 0; p < 4; p++) {
        if (p < 3) stage(p + 1, Bs[(p + 1) & 1]);
        if (p < 3) asm volatile("s_waitcnt vmcnt(4)" ::: "memory");
        else       asm volatile("s_waitcnt vmcnt(0)" ::: "memory");
        __builtin_amdgcn_s_barrier();             // buf[p&1] globally ready
        const u16* buf = Bs[p & 1];
#pragma unroll
        for (int ki = 0; ki < 8; ki++) {
#pragma unroll
            for (int nt = 0; nt < 4; nt++) {
                int nl = nt * 16 + l15;
                int cs = (ki * 4 + quad) ^ (nl & 7);
                short8 b = *(const short8*)(buf + nl * 256 + cs * 8);
                acc[p * 4 + nt] = __builtin_amdgcn_mfma_f32_16x16x32_bf16(za[ki], b, acc[p * 4 + nt], 0, 0, 0);
            }
        }
        if (p < 3) __builtin_amdgcn_s_barrier();  // all waves done reading buf[p&1]
    }
    // epilogue: out[q] = sigmoid( sum_col relu(acc + pb1[col]) * pW2[col] + pb2 )
    float rs[4] = {0.f, 0.f, 0.f, 0.f};
#pragma unroll
    for (int j = 0; j < 16; j++) {
        int col = (j >> 2) * 64 + (j & 3) * 16 + l15;
        float w2 = pW2[col], bb = pb1[col];
#pragma unroll
        for (int r = 0; r < 4; r++)
            rs[r] = fmaf(fmaxf(acc[j][r] + bb, 0.f), w2, rs[r]);
    }
#pragma unroll
    for (int m = 1; m < 16; m <<= 1) {
#pragma unroll
        for (int r = 0; r < 4; r++)
            rs[r] += __shfl_xor(rs[r], m, 64);
    }
    if (l15 == 0) {
        float b2v = pb2[0];
#pragma unroll
        for (int r = 0; r < 4; r++) {
            int qq = q0 + wave * 16 + quad * 4 + r;
            if (qq < Q) out[qq] = 1.0f / (1.0f + __expf(-(rs[r] + b2v)));
        }
    }
}

extern "C" void kernel_launch(void* const* d_in, const int* in_sizes, int n_in,
                              void* d_out, int out_size, void* d_ws, size_t ws_size,
                              hipStream_t stream) {
    const float* x      = (const float*)d_in[0];
    const int*   adj_row= (const int*)d_in[1];
    const int*   adj_col= (const int*)d_in[2];
    const int*   edges  = (const int*)d_in[3];
    const float* emb    = (const float*)d_in[4];
    const float* W1     = (const float*)d_in[5];
    const float* b1     = (const float*)d_in[6];
    const float* W2     = (const float*)d_in[7];
    const float* b2     = (const float*)d_in[8];
    const float* gamma  = (const float*)d_in[9];
    const float* beta   = (const float*)d_in[10];
    const float* pW1    = (const float*)d_in[11];
    const float* pb1    = (const float*)d_in[12];
    const float* pW2    = (const float*)d_in[13];
    const float* pb2    = (const float*)d_in[14];
    float* out = (float*)d_out;

    int N = in_sizes[0] / 128;
    int E = in_sizes[1];
    int Q = in_sizes[3] / 2;
    int NB = (N + 255) / 256;

    char* ws = (char*)d_ws;
    size_t off = 0;
    auto alloc = [&](size_t bytes) -> char* {
        char* p = ws + off;
        off += (bytes + 255) & ~(size_t)255;
        return p;
    };
    int*   deg_cnt = (int*)alloc((size_t)N * 4);
    int*   offs    = (int*)alloc((size_t)(N + 1) * 4);
    int*   cursor  = (int*)alloc((size_t)N * 4);
    float* dinv    = (float*)alloc((size_t)N * 4);
    int*   scol    = (int*)alloc((size_t)E * 4);
    float* sums    = (float*)alloc(512 * 4);
    float* coef    = (float*)alloc(512 * 4);
    int*   bsum    = (int*)alloc(256 * 4);
    int*   ebsum   = (int*)alloc(256 * 4);
    u16*   WT      = (u16*)alloc((size_t)3 * 65536 * 2);
    u16*   bufA    = (u16*)alloc((size_t)N * 256 * 2);
    u16*   bufB    = (u16*)alloc((size_t)N * 256 * 2);
    u16*   bufC    = (u16*)alloc((size_t)N * 256 * 2);

    hipMemsetAsync(deg_cnt, 0, (size_t)N * 4, stream);
    hipMemsetAsync(cursor, 0, (size_t)N * 4, stream);
    hipMemsetAsync(sums, 0, 512 * 4, stream);

    int eb  = (E + 255) / 256;
    int nb4 = (N * 64 + 255) / 256;
    int ab  = (N + 7) / 8;
    dim3 gemmGrid((N + 127) / 128, 2);

    count_deg<<<eb, 256, 0, stream>>>(adj_row, deg_cnt, E);
    deg_psum<<<NB, 256, 0, stream>>>(deg_cnt, bsum, N);
    scan_bsum<<<1, 256, 0, stream>>>(bsum, ebsum, NB, offs, N, E);
    write_offs<<<NB, 256, 0, stream>>>(deg_cnt, ebsum, offs, dinv, N);
    sort_edges<<<eb, 256, 0, stream>>>(adj_row, adj_col, offs, cursor, scol, E);
    prep_w<<<768, 256, 0, stream>>>(W1, W2, pW1, WT);
    concat_h0<<<nb4, 256, 0, stream>>>(emb, x, bufA, N);

    // conv1 (commuted): h1 = agg(h0) @ W1 + b1, with fused BN column stats
    aggregate2<0><<<ab, 256, 0, stream>>>(bufA, offs, scol, dinv, nullptr, bufB, N);
    gemm_big<1><<<gemmGrid, 256, 0, stream>>>(bufB, WT, b1, bufC, sums, N);
    bn_coef<<<1, 256, 0, stream>>>(sums, gamma, beta, coef, N);
    // conv2 (commuted): h2 = agg(relu(bn(h1))) @ W2 + b2, BN+ReLU fused into gather
    aggregate2<1><<<ab, 256, 0, stream>>>(bufC, offs, scol, dinv, coef, bufB, N);
    gemm_big<0><<<gemmGrid, 256, 0, stream>>>(bufB, WT + 65536, b2, bufC, nullptr, N);
    // link predictor
    predictor<<<(Q + 127) / 128, 512, 0, stream>>>(bufC, edges, edges + Q,
                                                   WT + 131072, pb1, pW2, pb2, out, Q);
}